// Round 1
// baseline (246.027 us; speedup 1.0000x reference)
//
#include <hip/hip_runtime.h>
#include <math.h>

// Sizes (fixed by the reference)
#define NB    16     // batch
#define NC    16     // conv channels
#define HW1   24     // conv out spatial
#define P1    576    // 24*24
#define HW2   12     // pooled spatial
#define P2    144    // 12*12
#define KK    5
#define PATCH 25
#define NU    10     // units
#define EPSV  1e-4f
#define DSCALE 1.25f // 1/(1-0.2)

// ---------------- Kernel 1: conv (mu) + per-(b,c) batchnorm partial sums ----
__global__ __launch_bounds__(256) void k_conv(
    const float* __restrict__ x,        // [B,28,28,1]
    const float* __restrict__ wconv,    // [5,5,1,16]
    float* __restrict__ mu_ws,          // [B,576,16]
    float* __restrict__ psum,           // [B,16]
    float* __restrict__ psq)            // [B,16]
{
    __shared__ float x_s[784];
    __shared__ float w_s[400];
    __shared__ float red_a[256], red_b[256];
    const int b = blockIdx.x, t = threadIdx.x;

    for (int j = t; j < 784; j += 256) x_s[j] = x[b * 784 + j];
    for (int j = t; j < 400; j += 256) w_s[j] = wconv[j];
    __syncthreads();

    const int c = t & 15, g = t >> 4;   // 16 channels x 16 spatial groups
    float s = 0.f, sq = 0.f;
    for (int k = 0; k < 36; k++) {
        const int i = g * 36 + k;
        const int y = i / 24, xx = i % 24;
        float acc = 0.f;
#pragma unroll
        for (int dy = 0; dy < 5; dy++)
#pragma unroll
            for (int dx = 0; dx < 5; dx++)
                acc = fmaf(x_s[(y + dy) * 28 + xx + dx], w_s[(dy * 5 + dx) * 16 + c], acc);
        mu_ws[b * 9216 + i * 16 + c] = acc;
        s += acc;
        sq = fmaf(acc, acc, sq);
    }
    red_a[t] = s; red_b[t] = sq;
    __syncthreads();
    if (t < 16) {
        float ts = 0.f, tq = 0.f;
        for (int j = 0; j < 16; j++) { ts += red_a[t + j * 16]; tq += red_b[t + j * 16]; }
        psum[b * 16 + t] = ts;
        psq[b * 16 + t]  = tq;
    }
}

// ---------------- Kernel 2: BN + ELU + pool + dropout + FC (mu & Sigma) ----
__global__ __launch_bounds__(256) void k_main(
    const float* __restrict__ x,        // [B,28,28,1]
    const int* __restrict__ dmask,      // [B,12,12,16] (0/1)
    const float* __restrict__ wsconv,   // [16]
    const float* __restrict__ wfc,      // [2304,10]
    const float* __restrict__ wsfc,     // [10]
    const float* __restrict__ mu_ws,    // [B,576,16]
    const float* __restrict__ psum,
    const float* __restrict__ psq,
    float* __restrict__ out)            // [160] mu_out ++ [1600] Sigma_out
{
    __shared__ float x_s[784];
    __shared__ float mn_s[9216];        // normalized conv out, [i][c]
    __shared__ float PN_s[576];         // patch sq-norms
    __shared__ float mean_s[16], istd_s[16], sc_s[16], spfc_s[10];
    __shared__ int   I28_s[2304];       // [c][q] -> iy*28+ix (argmax pos)
    __shared__ float f_s[2304];         // [c][q] = 1.25*m*g
    __shared__ float mud_s[2304];       // [q][c] flat == fc row index
    __shared__ float T_s[4000];         // [c][p][u]
    __shared__ float W_s[1440];         // one channel of W1: [q][u]
    __shared__ float red_a[256], red_b[256];
    __shared__ float pmo_s[160];

    const int b = blockIdx.x, t = threadIdx.x;

    // Phase 1: load x; finalize batchnorm stats; softplus terms
    for (int j = t; j < 784; j += 256) x_s[j] = x[b * 784 + j];
    if (t < 16) {
        float ts = 0.f, tq = 0.f;
        for (int bb = 0; bb < 16; bb++) { ts += psum[bb * 16 + t]; tq += psq[bb * 16 + t]; }
        const float mean = ts * (1.f / 9216.f);
        const float var  = tq * (1.f / 9216.f) - mean * mean;
        mean_s[t] = mean;
        istd_s[t] = 1.f / sqrtf(var + EPSV);
        const float sp = log1pf(expf(wsconv[t]));
        sc_s[t] = sp / (var + EPSV);
    }
    if (t < 10) spfc_s[t] = log1pf(expf(wsfc[t]));
    __syncthreads();

    // Phase 2: normalize conv out into LDS; patch norms
    for (int j = t; j < 9216; j += 256) {
        const int cc = j & 15;
        mn_s[j] = (mu_ws[b * 9216 + j] - mean_s[cc]) * istd_s[cc];
    }
    for (int i = t; i < 576; i += 256) {
        const int y = i / 24, xx = i % 24;
        float acc = 0.f;
#pragma unroll
        for (int dy = 0; dy < 5; dy++)
#pragma unroll
            for (int dx = 0; dx < 5; dx++) {
                const float v = x_s[(y + dy) * 28 + xx + dx];
                acc = fmaf(v, v, acc);
            }
        PN_s[i] = acc;
    }
    __syncthreads();

    // Phase 3: maxpool (argmax, strict-first), dropout, f, mu_drop, tr/mumu partials
    float mm_part = 0.f, tr_part = 0.f;
    for (int k = 0; k < 9; k++) {
        const int e = t * 9 + k;            // 0..2303
        const int q = e >> 4, c = e & 15;
        const int h = q / 12, w = q % 12;
        const int y0 = 2 * h, x0 = 2 * w;
        const int i0 = (y0 * 24 + x0) * 16 + c;
        const float v00 = mn_s[i0];
        const float v01 = mn_s[i0 + 16];
        const float v10 = mn_s[i0 + 24 * 16];
        const float v11 = mn_s[i0 + 25 * 16];
        float best = v00; int arg = 0;
        if (v01 > best) { best = v01; arg = 1; }
        if (v10 > best) { best = v10; arg = 2; }
        if (v11 > best) { best = v11; arg = 3; }
        const int yy = y0 + (arg >> 1), xx2 = x0 + (arg & 1);
        const float m = (dmask[((b * 12 + h) * 12 + w) * 16 + c] != 0) ? 1.f : 0.f;
        const float gg   = best > 0.f ? 1.f : expf(best);
        const float eluv = best > 0.f ? best : expm1f(best);
        const float fq = DSCALE * m * gg;
        const float md = DSCALE * m * eluv;
        f_s[c * 144 + q]   = fq;
        I28_s[c * 144 + q] = yy * 28 + xx2;
        mud_s[e] = md;
        mm_part = fmaf(md, md, mm_part);
        tr_part += sc_s[c] * fq * fq * PN_s[yy * 24 + xx2];
    }
    red_a[t] = mm_part; red_b[t] = tr_part;
    __syncthreads();
    for (int s = 128; s > 0; s >>= 1) {
        if (t < s) { red_a[t] += red_a[t + s]; red_b[t] += red_b[t + s]; }
        __syncthreads();
    }
    // red_a[0] = mumu, red_b[0] = trace

    // Phase 4: mu_out = mud_flat @ wfc
    if (t < 160) {
        const int u = t % 10, ch = t / 10;
        const int base = ch * 144;
        float acc = 0.f;
        for (int j = 0; j < 144; j++)
            acc = fmaf(mud_s[base + j], wfc[(base + j) * 10 + u], acc);
        pmo_s[t] = acc;
    }
    __syncthreads();
    if (t < 10) {
        float acc = 0.f;
        for (int k2 = 0; k2 < 16; k2++) acc += pmo_s[k2 * 10 + t];
        out[b * 10 + t] = acc;
    }

    // Phase 5: T[c,p,u] = sum_q W1[c,q,u] * f[c,q] * Xm[I_q, p]
    int p = 0, u = 0, poff = 0;
    const bool active = (t < 250);
    if (active) { p = t / 10; u = t % 10; poff = (p / 5) * 28 + (p % 5); }
    for (int c = 0; c < 16; c++) {
        __syncthreads();
        for (int j = t; j < 1440; j += 256) W_s[j] = wfc[c * 1440 + j];
        __syncthreads();
        if (active) {
            float acc = 0.f;
            const float* fp = &f_s[c * 144];
            const int*   ip = &I28_s[c * 144];
            for (int q = 0; q < 144; q++) {
                const float fq = fp[q];
                if (fq != 0.f)
                    acc = fmaf(fq * W_s[q * 10 + u], x_s[ip[q] + poff], acc);
            }
            T_s[(c * 25 + p) * 10 + u] = acc;
        }
    }
    __syncthreads();

    // Phase 6: Sigma_out[u,v] = sum_c sc_c sum_p T[c,p,u]T[c,p,v] + diag
    if (t < 100) {
        const int uu = t / 10, vv = t % 10;
        float acc = 0.f;
        for (int c = 0; c < 16; c++) {
            const float s = sc_s[c];
            const float* Tc = &T_s[c * 250];
            float a2 = 0.f;
#pragma unroll
            for (int pp = 0; pp < 25; pp++)
                a2 = fmaf(Tc[pp * 10 + uu], Tc[pp * 10 + vv], a2);
            acc = fmaf(s, a2, acc);
        }
        if (uu == vv) acc += spfc_s[uu] * (red_b[0] + red_a[0]);
        out[160 + b * 100 + t] = acc;
    }
}

extern "C" void kernel_launch(void* const* d_in, const int* in_sizes, int n_in,
                              void* d_out, int out_size, void* d_ws, size_t ws_size,
                              hipStream_t stream) {
    const float* x      = (const float*)d_in[0];
    const int*   dmask  = (const int*)d_in[1];
    const float* wconv  = (const float*)d_in[2];
    const float* wsconv = (const float*)d_in[3];
    const float* wfc    = (const float*)d_in[4];
    const float* wsfc   = (const float*)d_in[5];
    float* out = (float*)d_out;

    float* ws    = (float*)d_ws;
    float* mu_ws = ws;                 // 147456 floats
    float* psum  = ws + 147456;        // 256
    float* psq   = psum + 256;         // 256

    k_conv<<<16, 256, 0, stream>>>(x, wconv, mu_ws, psum, psq);
    k_main<<<16, 256, 0, stream>>>(x, dmask, wsconv, wfc, wsfc, mu_ws, psum, psq, out);
}

// Round 2
// 23.613 us; speedup vs baseline: 10.4190x; 10.4190x over previous
//
#include <hip/hip_runtime.h>
#include <math.h>

#define EPSV   1e-4f
#define DSCALE 1.25f   // 1/(1-0.2)

// ws layout (floats):
//   pooledv [256][144]   off 0        (raw conv max per (b,c,q))
//   pooledi [256][144]   off 36864    (int: argmax pos as yy*28+xx)
//   psum    [256]        off 73728    (per (b,c) sum of 576 conv outs)
//   psq     [256]        off 73984
//   moP     [256][10]    off 74240    (per (b,c) mu_out partial)
//   s1P     [256][100]   off 76800    (per (b,c) Sigma partial, sc-scaled)
//   tmP     [256][2]     off 102400   (per (b,c) [trace, mu.mu] partials)

// ---------- kA: conv + raw-max pool + BN partial sums, one block per (b,c) ----
__global__ __launch_bounds__(256) void kA(
    const float* __restrict__ x,      // [B,28,28,1]
    const float* __restrict__ wconv,  // [5,5,1,16]
    float* __restrict__ pooledv, int* __restrict__ pooledi,
    float* __restrict__ psum, float* __restrict__ psq)
{
    __shared__ float x_s[784], w_s[25], mu_s[576];
    __shared__ float ra[256], rb[256];
    const int bc = blockIdx.x, b = bc >> 4, c = bc & 15, t = threadIdx.x;

    for (int j = t; j < 784; j += 256) x_s[j] = x[b * 784 + j];
    if (t < 25) w_s[t] = wconv[t * 16 + c];
    __syncthreads();

    float s = 0.f, sq = 0.f;
    for (int i = t; i < 576; i += 256) {
        const int y = i / 24, xx = i % 24;
        float acc = 0.f;
#pragma unroll
        for (int dy = 0; dy < 5; dy++)
#pragma unroll
            for (int dx = 0; dx < 5; dx++)
                acc = fmaf(x_s[(y + dy) * 28 + xx + dx], w_s[dy * 5 + dx], acc);
        mu_s[i] = acc; s += acc; sq = fmaf(acc, acc, sq);
    }
    ra[t] = s; rb[t] = sq;
    __syncthreads();

    // 2x2/2 max pool on RAW conv values (BN is monotone -> same argmax, first-max ties)
    if (t < 144) {
        const int h = t / 12, w2 = t % 12, y0 = 2 * h, x0 = 2 * w2;
        const int i0 = y0 * 24 + x0;
        const float v00 = mu_s[i0], v01 = mu_s[i0 + 1];
        const float v10 = mu_s[i0 + 24], v11 = mu_s[i0 + 25];
        float best = v00; int arg = 0;
        if (v01 > best) { best = v01; arg = 1; }
        if (v10 > best) { best = v10; arg = 2; }
        if (v11 > best) { best = v11; arg = 3; }
        const int yy = y0 + (arg >> 1), xx = x0 + (arg & 1);
        pooledv[bc * 144 + t] = best;
        pooledi[bc * 144 + t] = yy * 28 + xx;
    }
    for (int sft = 128; sft > 0; sft >>= 1) {
        if (t < sft) { ra[t] += ra[t + sft]; rb[t] += rb[t + sft]; }
        __syncthreads();
    }
    if (t == 0) { psum[bc] = ra[0]; psq[bc] = rb[0]; }
}

// ---------- kB: BN+ELU+dropout+T+partials, one block per (b,c) ----
__global__ __launch_bounds__(256) void kB(
    const float* __restrict__ x,
    const int* __restrict__ dmask,    // [B,12,12,16]
    const float* __restrict__ wsconv, // [16]
    const float* __restrict__ wfc,    // [2304,10]
    const float* __restrict__ pooledv, const int* __restrict__ pooledi,
    const float* __restrict__ psum, const float* __restrict__ psq,
    float* __restrict__ moP, float* __restrict__ s1P, float* __restrict__ tmP)
{
    __shared__ float x_s[784];
    __shared__ float W2_s[1440];   // spatial-major rows (q*16+c) for mu_out
    __shared__ float fW_s[1440];   // f[q] * W1[c,q,u]  (channel-major rows c*144+q)
    __shared__ float Xg_s[3600];   // [q][p] gathered patches at argmax
    __shared__ float f_s[144], mud_s[144], trq_s[144], mmq_s[144];
    __shared__ int   I_s[144];
    __shared__ float T_s[250];     // [p][u]
    __shared__ float ps_s[16], pq_s[16], stat_s[4];
    const int bc = blockIdx.x, b = bc >> 4, c = bc & 15, t = threadIdx.x;

    for (int j = t; j < 784; j += 256) x_s[j] = x[b * 784 + j];
    for (int j = t; j < 1440; j += 256) {
        const int q = j / 10, u = j - q * 10;
        W2_s[j] = wfc[(q * 16 + c) * 10 + u];
    }
    if (t < 16) { ps_s[t] = psum[t * 16 + c]; pq_s[t] = psq[t * 16 + c]; }
    __syncthreads();

    if (t == 0) {
        float ts = 0.f, tq = 0.f;
        for (int i = 0; i < 16; i++) { ts += ps_s[i]; tq += pq_s[i]; }
        const float mean = ts * (1.f / 9216.f);
        const float var  = tq * (1.f / 9216.f) - mean * mean;
        stat_s[0] = mean;
        stat_s[1] = 1.f / sqrtf(var + EPSV);
        stat_s[2] = log1pf(expf(wsconv[c])) / (var + EPSV);  // sc
    }
    __syncthreads();

    if (t < 144) {
        const float mean = stat_s[0], istd = stat_s[1], sc = stat_s[2];
        const float vn = (pooledv[bc * 144 + t] - mean) * istd;
        const int i28 = pooledi[bc * 144 + t];
        const int h = t / 12, w2 = t % 12;
        const float m = (dmask[((b * 12 + h) * 12 + w2) * 16 + c] != 0) ? 1.f : 0.f;
        const float g  = vn > 0.f ? 1.f : expf(vn);
        const float el = vn > 0.f ? vn  : expm1f(vn);
        const float fq = DSCALE * m * g;
        const float md = DSCALE * m * el;
        f_s[t] = fq; mud_s[t] = md; I_s[t] = i28;
        float pn = 0.f;
#pragma unroll
        for (int dy = 0; dy < 5; dy++)
#pragma unroll
            for (int dx = 0; dx < 5; dx++) {
                const float v = x_s[i28 + dy * 28 + dx];
                pn = fmaf(v, v, pn);
            }
        trq_s[t] = sc * fq * fq * pn;
        mmq_s[t] = md * md;
    }
    __syncthreads();

    for (int j = t; j < 1440; j += 256) fW_s[j] = f_s[j / 10] * wfc[c * 1440 + j];
    for (int e = t; e < 3600; e += 256) {
        const int q = e / 25, p = e - q * 25;
        Xg_s[e] = x_s[I_s[q] + (p / 5) * 28 + (p % 5)];
    }
    __syncthreads();

    if (t < 250) {                       // T[p,u] = sum_q fW[q,u] * Xg[q,p]
        const int p = t / 10, u = t - p * 10;
        float acc = 0.f;
#pragma unroll 8
        for (int q = 0; q < 144; q++)
            acc = fmaf(fW_s[q * 10 + u], Xg_s[q * 25 + p], acc);
        T_s[p * 10 + u] = acc;
    } else if (t == 250) {
        float a = 0.f;
        for (int q = 0; q < 144; q++) a += trq_s[q];
        tmP[bc * 2 + 0] = a;
    } else if (t == 251) {
        float a = 0.f;
        for (int q = 0; q < 144; q++) a += mmq_s[q];
        tmP[bc * 2 + 1] = a;
    }
    __syncthreads();

    if (t < 100) {                       // sc * T^T T  -> Sigma partial
        const int u = t / 10, v = t - u * 10;
        float acc = 0.f;
#pragma unroll
        for (int p = 0; p < 25; p++)
            acc = fmaf(T_s[p * 10 + u], T_s[p * 10 + v], acc);
        s1P[bc * 100 + t] = stat_s[2] * acc;
    } else if (t < 110) {                // mu_out partial (spatial-major rows)
        const int u = t - 100;
        float a = 0.f;
#pragma unroll 8
        for (int q = 0; q < 144; q++) a = fmaf(mud_s[q], W2_s[q * 10 + u], a);
        moP[bc * 10 + u] = a;
    }
}

// ---------- kC: reduce over c, add diagonal, write outputs ----
__global__ __launch_bounds__(128) void kC(
    const float* __restrict__ wsfc,
    const float* __restrict__ moP, const float* __restrict__ s1P,
    const float* __restrict__ tmP, float* __restrict__ out)
{
    __shared__ float red[32];
    __shared__ float trmm_s;
    const int b = blockIdx.x, t = threadIdx.x;
    if (t < 32) red[t] = tmP[(b * 16 + (t >> 1)) * 2 + (t & 1)];
    __syncthreads();
    if (t == 0) { float a = 0.f; for (int i = 0; i < 32; i++) a += red[i]; trmm_s = a; }
    __syncthreads();
    if (t < 100) {
        const int u = t / 10, v = t - u * 10;
        float acc = 0.f;
        for (int cc = 0; cc < 16; cc++) acc += s1P[(b * 16 + cc) * 100 + t];
        if (u == v) acc += log1pf(expf(wsfc[u])) * trmm_s;
        out[160 + b * 100 + t] = acc;
    } else if (t < 110) {
        const int u = t - 100;
        float a = 0.f;
        for (int cc = 0; cc < 16; cc++) a += moP[(b * 16 + cc) * 10 + u];
        out[b * 10 + u] = a;
    }
}

extern "C" void kernel_launch(void* const* d_in, const int* in_sizes, int n_in,
                              void* d_out, int out_size, void* d_ws, size_t ws_size,
                              hipStream_t stream) {
    const float* x      = (const float*)d_in[0];
    const int*   dmask  = (const int*)d_in[1];
    const float* wconv  = (const float*)d_in[2];
    const float* wsconv = (const float*)d_in[3];
    const float* wfc    = (const float*)d_in[4];
    const float* wsfc   = (const float*)d_in[5];
    float* out = (float*)d_out;

    float* ws      = (float*)d_ws;
    float* pooledv = ws;
    int*   pooledi = (int*)(ws + 36864);
    float* psum    = ws + 73728;
    float* psq     = ws + 73984;
    float* moP     = ws + 74240;
    float* s1P     = ws + 76800;
    float* tmP     = ws + 102400;

    kA<<<256, 256, 0, stream>>>(x, wconv, pooledv, pooledi, psum, psq);
    kB<<<256, 256, 0, stream>>>(x, dmask, wsconv, wfc, pooledv, pooledi,
                                psum, psq, moP, s1P, tmP);
    kC<<<16, 128, 0, stream>>>(wsfc, moP, s1P, tmP, out);
}